// Round 3
// baseline (845.351 us; speedup 1.0000x reference)
//
#include <hip/hip_runtime.h>
#include <math.h>

#define TT 512
#define BB 512
#define FF 14
#define H1 32
#define H2 64
#define G1 128   // 4*H1
#define G2 256   // 4*H2

__device__ __forceinline__ float sigmoidf_(float x) {
    return 1.0f / (1.0f + __expf(-x));
}
__device__ __forceinline__ float tanhf_(float x) {
    float e = __expf(-2.0f * fabsf(x));
    float t = (1.0f - e) / (1.0f + e);
    return copysignf(t, x);
}

// Pin a float into a VGPR: forbids rematerialization / demotion to scratch.
#define PIN(v) asm volatile("" : "+v"(v))

// One block per batch row, 256 threads (4 waves), 2 blocks/CU (grid-limited).
// amdgpu_waves_per_eu(2,2): clamp occupancy at exactly what the grid can use,
// freeing the full 256-VGPR budget so weights stay register-resident.
__global__ __launch_bounds__(256)
__attribute__((amdgpu_waves_per_eu(2, 2)))
void lstm3_kernel(
    const float* __restrict__ x,
    const float* __restrict__ Wih1, const float* __restrict__ Whh1,
    const float* __restrict__ bih1, const float* __restrict__ bhh1,
    const float* __restrict__ Wih2, const float* __restrict__ Whh2,
    const float* __restrict__ bih2, const float* __restrict__ bhh2,
    const float* __restrict__ Wfc1, const float* __restrict__ bfc1,
    const float* __restrict__ Wfc2, const float* __restrict__ bfc2,
    const float* __restrict__ Wfc,  const float* __restrict__ bfc,
    float* __restrict__ out)
{
    const int row = blockIdx.x;
    const int t   = threadIdx.x;

    __shared__ __align__(16) float xbuf[2][16];   // x_t double buffer (14 + pad)
    __shared__ __align__(16) float h1s[H1];
    __shared__ __align__(16) float h2s[H2];
    __shared__ float g1buf[G1];
    __shared__ float g2buf[G2];
    __shared__ float mlp1[8];
    __shared__ float mlp2[8];

    // ---- layer-2 weights for gate t (96 floats), pinned into VGPRs ----
    float w2[H1 + H2];
    {
        const float4* p = (const float4*)(Wih2 + t * H1);
        #pragma unroll
        for (int k = 0; k < 8; ++k) {
            float4 v = p[k];
            w2[4 * k + 0] = v.x; w2[4 * k + 1] = v.y;
            w2[4 * k + 2] = v.z; w2[4 * k + 3] = v.w;
        }
        const float4* q = (const float4*)(Whh2 + t * H2);
        #pragma unroll
        for (int k = 0; k < 16; ++k) {
            float4 v = q[k];
            w2[H1 + 4 * k + 0] = v.x; w2[H1 + 4 * k + 1] = v.y;
            w2[H1 + 4 * k + 2] = v.z; w2[H1 + 4 * k + 3] = v.w;
        }
        #pragma unroll
        for (int k = 0; k < H1 + H2; ++k) PIN(w2[k]);
    }
    float b2r = bih2[t] + bhh2[t];
    PIN(b2r);

    // ---- layer-1 weights for gate t-128 (threads 128..255), pinned ----
    // w1[0..13] = Wih1 row, w1[14..15] = 0 pad, w1[16..47] = Whh1 row
    float w1[48];
    float b1r = 0.0f;
    if (t >= 128) {
        const int g = t - 128;
        #pragma unroll
        for (int k = 0; k < FF; ++k) w1[k] = Wih1[g * FF + k];
        w1[14] = 0.0f; w1[15] = 0.0f;
        const float4* q = (const float4*)(Whh1 + g * H1);
        #pragma unroll
        for (int k = 0; k < 8; ++k) {
            float4 v = q[k];
            w1[16 + 4 * k + 0] = v.x; w1[16 + 4 * k + 1] = v.y;
            w1[16 + 4 * k + 2] = v.z; w1[16 + 4 * k + 3] = v.w;
        }
        b1r = bih1[g] + bhh1[g];
        #pragma unroll
        for (int k = 0; k < 48; ++k) PIN(w1[k]);
        PIN(b1r);
    }

    float c1r = 0.0f;   // layer-1 cell state, threads 0..31
    float xreg = 0.0f;  // x prefetch register, threads 64..77

    if (t < H1) h1s[t] = 0.0f;
    if (t < H2) h2s[t] = 0.0f;
    if (t >= 64 && t < 64 + FF) {
        const int f = t - 64;
        xbuf[0][f] = x[(size_t)0 * BB * FF + row * FF + f];
        xreg       = x[(size_t)1 * BB * FF + row * FF + f];
    }
    if (t == 78) { xbuf[0][14] = 0.f; xbuf[0][15] = 0.f; xbuf[1][14] = 0.f; xbuf[1][15] = 0.f; }
    __syncthreads();

    for (int step = 0; step < TT; ++step) {
        // ===== Phase A =====
        // waves 2,3 (t>=128): layer-1 gates;  wave 0 (t<64): h2 update of prev
        // step;  wave 1 lanes 64..77: stage next x.
        if (t >= 128) {
            const float4* xv  = (const float4*)xbuf[step & 1];
            const float4* h1v = (const float4*)h1s;
            float a0 = b1r, a1 = 0.f, a2 = 0.f, a3 = 0.f;
            #pragma unroll
            for (int k = 0; k < 4; ++k) {
                float4 v = xv[k];
                a0 = fmaf(v.x, w1[4 * k + 0], a0);
                a1 = fmaf(v.y, w1[4 * k + 1], a1);
                a2 = fmaf(v.z, w1[4 * k + 2], a2);
                a3 = fmaf(v.w, w1[4 * k + 3], a3);
            }
            #pragma unroll
            for (int k = 0; k < 8; ++k) {
                float4 v = h1v[k];
                a0 = fmaf(v.x, w1[16 + 4 * k + 0], a0);
                a1 = fmaf(v.y, w1[16 + 4 * k + 1], a1);
                a2 = fmaf(v.z, w1[16 + 4 * k + 2], a2);
                a3 = fmaf(v.w, w1[16 + 4 * k + 3], a3);
            }
            g1buf[t - 128] = (a0 + a1) + (a2 + a3);
        } else if (t < H2) {
            if (step > 0) {
                const float ig = g2buf[t];
                const float gg = g2buf[t + 128];
                const float og = g2buf[t + 192];
                const float cn = sigmoidf_(ig) * tanhf_(gg);
                h2s[t] = sigmoidf_(og) * tanhf_(cn);
            }
        } else if (t < 64 + FF) {
            const int f = t - 64;
            xbuf[(step + 1) & 1][f] = xreg;
            const int tn = (step + 2 < TT) ? (step + 2) : (TT - 1);
            xreg = x[(size_t)tn * BB * FF + row * FF + f];
        }
        __syncthreads();

        // ===== Phase B: h1/c1 update (threads 0..31) =====
        if (t < H1) {
            const float ig = g1buf[t];
            const float fg = g1buf[t + 32];
            const float gg = g1buf[t + 64];
            const float og = g1buf[t + 96];
            const float cn = sigmoidf_(fg) * c1r + sigmoidf_(ig) * tanhf_(gg);
            c1r = cn;
            h1s[t] = sigmoidf_(og) * tanhf_(cn);
        }
        __syncthreads();

        // ===== Phase C: layer-2 gates (all 256 threads) =====
        {
            const float4* h1v = (const float4*)h1s;
            const float4* h2v = (const float4*)h2s;
            float a0 = b2r, a1 = 0.f, a2 = 0.f, a3 = 0.f;
            #pragma unroll
            for (int k = 0; k < 8; ++k) {
                float4 v = h1v[k];
                a0 = fmaf(v.x, w2[4 * k + 0], a0);
                a1 = fmaf(v.y, w2[4 * k + 1], a1);
                a2 = fmaf(v.z, w2[4 * k + 2], a2);
                a3 = fmaf(v.w, w2[4 * k + 3], a3);
            }
            #pragma unroll
            for (int k = 0; k < 16; ++k) {
                float4 v = h2v[k];
                a0 = fmaf(v.x, w2[H1 + 4 * k + 0], a0);
                a1 = fmaf(v.y, w2[H1 + 4 * k + 1], a1);
                a2 = fmaf(v.z, w2[H1 + 4 * k + 2], a2);
                a3 = fmaf(v.w, w2[H1 + 4 * k + 3], a3);
            }
            g2buf[t] = (a0 + a1) + (a2 + a3);
        }
        __syncthreads();
    }

    // ---- final h2 update (step TT-1) ----
    if (t < H2) {
        const float ig = g2buf[t];
        const float gg = g2buf[t + 128];
        const float og = g2buf[t + 192];
        const float cn = sigmoidf_(ig) * tanhf_(gg);
        h2s[t] = sigmoidf_(og) * tanhf_(cn);
    }
    __syncthreads();

    // ---- MLP head ----
    if (t < 8) {
        float a = bfc1[t];
        #pragma unroll
        for (int k = 0; k < H2; ++k)
            a = fmaf(fmaxf(h2s[k], 0.0f), Wfc1[t * H2 + k], a);
        mlp1[t] = fmaxf(a, 0.0f);
    }
    __syncthreads();
    if (t < 8) {
        float a = bfc2[t];
        #pragma unroll
        for (int k = 0; k < 8; ++k) a = fmaf(mlp1[k], Wfc2[t * 8 + k], a);
        mlp2[t] = fmaxf(a, 0.0f);
    }
    __syncthreads();
    if (t == 0) {
        float a = bfc[0];
        #pragma unroll
        for (int k = 0; k < 8; ++k) a = fmaf(mlp2[k], Wfc[k], a);
        out[row] = a;
    }
}

extern "C" void kernel_launch(void* const* d_in, const int* in_sizes, int n_in,
                              void* d_out, int out_size, void* d_ws, size_t ws_size,
                              hipStream_t stream) {
    const float* x    = (const float*)d_in[0];
    const float* Wih1 = (const float*)d_in[1];
    const float* Whh1 = (const float*)d_in[2];
    const float* bih1 = (const float*)d_in[3];
    const float* bhh1 = (const float*)d_in[4];
    const float* Wih2 = (const float*)d_in[5];
    const float* Whh2 = (const float*)d_in[6];
    const float* bih2 = (const float*)d_in[7];
    const float* bhh2 = (const float*)d_in[8];
    const float* Wfc1 = (const float*)d_in[9];
    const float* bfc1 = (const float*)d_in[10];
    const float* Wfc2 = (const float*)d_in[11];
    const float* bfc2 = (const float*)d_in[12];
    const float* Wfc  = (const float*)d_in[13];
    const float* bfc  = (const float*)d_in[14];
    float* out = (float*)d_out;

    lstm3_kernel<<<dim3(BB), dim3(256), 0, stream>>>(
        x, Wih1, Whh1, bih1, bhh1, Wih2, Whh2, bih2, bhh2,
        Wfc1, bfc1, Wfc2, bfc2, Wfc, bfc, out);
}

// Round 4
// 700.042 us; speedup vs baseline: 1.2076x; 1.2076x over previous
//
#include <hip/hip_runtime.h>
#include <math.h>

#define TT 512
#define BB 512
#define FF 14
#define H1 32
#define H2 64
#define G1 128   // 4*H1
#define G2 256   // 4*H2

__device__ __forceinline__ float sigmoidf_(float x) {
    return 1.0f / (1.0f + __expf(-x));
}
__device__ __forceinline__ float tanhf_(float x) {
    float e = __expf(-2.0f * fabsf(x));
    float t = (1.0f - e) / (1.0f + e);
    return copysignf(t, x);
}

// One block per batch row, 512 threads (8 waves), 2 blocks/CU.
// Every thread owns HALF of a layer-2 gate row (48 floats = 12 float4);
// threads 0..255 additionally own half of a layer-1 gate row (24 floats).
// Max per-thread weight footprint 72 floats -> fits a 128-VGPR budget with
// room to spare, so the allocator keeps weights register-resident (rounds
// 1-3 proved it refuses to hold 96-144 floats and re-fetches from L2 at
// ~31 TB/s = the L2 ceiling). Halves are wave-aligned so all LDS state
// reads are lane-uniform broadcasts (conflict-free).
__global__ __launch_bounds__(512)
__attribute__((amdgpu_waves_per_eu(4)))
void lstm3_kernel(
    const float* __restrict__ x,
    const float* __restrict__ Wih1, const float* __restrict__ Whh1,
    const float* __restrict__ bih1, const float* __restrict__ bhh1,
    const float* __restrict__ Wih2, const float* __restrict__ Whh2,
    const float* __restrict__ bih2, const float* __restrict__ bhh2,
    const float* __restrict__ Wfc1, const float* __restrict__ bfc1,
    const float* __restrict__ Wfc2, const float* __restrict__ bfc2,
    const float* __restrict__ Wfc,  const float* __restrict__ bfc,
    float* __restrict__ out)
{
    const int row = blockIdx.x;
    const int t   = threadIdx.x;

    // s12 = [h1(32) | h2(64)] : the layer-2 state vector, contiguous.
    // sx1 = [x(14) | pad(2) | h1(32)] : the layer-1 state vector, x+h1
    //       double-buffered so staging/updates overlap reads.
    __shared__ __align__(16) float s12[96];
    __shared__ __align__(16) float sx1[2][48];
    __shared__ float g1part[256];   // [half*128 + gate]
    __shared__ float g2part[512];   // [half*256 + gate]
    __shared__ float mlp1[8];
    __shared__ float mlp2[8];

    const int g2  = t & 255;        // layer-2 gate owned by this thread
    const int h2h = t >> 8;         // which half of the 96-long dot
    const int g1  = t & 127;        // layer-1 gate (threads 0..255)
    const int h1h = (t >> 7) & 1;   // which half of the 48-long dot

    // ---- layer-2 weights: 12 float4 (48 floats) per thread ----
    float4 w2[12];
    if (h2h == 0) {
        const float4* p = (const float4*)(Wih2 + g2 * H1);
        #pragma unroll
        for (int k = 0; k < 8; ++k) w2[k] = p[k];
        const float4* q = (const float4*)(Whh2 + g2 * H2);
        #pragma unroll
        for (int k = 0; k < 4; ++k) w2[8 + k] = q[k];
    } else {
        const float4* q = (const float4*)(Whh2 + g2 * H2);
        #pragma unroll
        for (int k = 0; k < 12; ++k) w2[k] = q[4 + k];
    }
    const float b2r = (h2h == 0) ? (bih2[g2] + bhh2[g2]) : 0.0f;

    // ---- layer-1 weights: 6 float4 (24 floats), threads 0..255 ----
    float4 w1[6];
    float b1r = 0.0f;
    if (t < 256) {
        if (h1h == 0) {
            // P[0..23] = [Wih1 row (14) | 0,0 | Whh1 row first 8]
            float tmp[16];
            #pragma unroll
            for (int k = 0; k < FF; ++k) tmp[k] = Wih1[g1 * FF + k];
            tmp[14] = 0.0f; tmp[15] = 0.0f;
            #pragma unroll
            for (int k = 0; k < 4; ++k)
                w1[k] = make_float4(tmp[4 * k], tmp[4 * k + 1], tmp[4 * k + 2], tmp[4 * k + 3]);
            const float4* q = (const float4*)(Whh1 + g1 * H1);
            w1[4] = q[0];
            w1[5] = q[1];
            b1r = bih1[g1] + bhh1[g1];
        } else {
            // P[24..47] = Whh1 row elements 8..31
            const float4* q = (const float4*)(Whh1 + g1 * H1);
            #pragma unroll
            for (int k = 0; k < 6; ++k) w1[k] = q[2 + k];
        }
    }

    float c1r  = 0.0f;  // layer-1 cell state, threads 0..31
    float xreg = 0.0f;  // x prefetch, threads 256..269

    // ---- init state / stage x[0], prefetch x[1] ----
    if (t < 96) s12[t] = 0.0f;
    if (t < 32) sx1[0][16 + t] = 0.0f;
    if (t >= 256 && t < 256 + FF) {
        const int f = t - 256;
        sx1[0][f] = x[(size_t)0 * BB * FF + row * FF + f];
        xreg      = x[(size_t)1 * BB * FF + row * FF + f];
    }
    if (t == 280) { sx1[0][14] = 0.f; sx1[0][15] = 0.f; sx1[1][14] = 0.f; sx1[1][15] = 0.f; }
    __syncthreads();

    for (int step = 0; step < TT; ++step) {
        const int sb = step & 1;
        const int nb = sb ^ 1;

        // ===== P1 =====
        // t<256            : layer-1 half-dots (uniform broadcast reads)
        // t in [320,384)   : h2 update of PREVIOUS step (reads g2part)
        // t in [256,256+FF): stage x[step+1] into the other buffer
        if (t < 256) {
            const float4* sv = (const float4*)(sx1[sb]) + h1h * 6;
            float a0 = b1r, a1 = 0.f, a2 = 0.f, a3 = 0.f;
            #pragma unroll
            for (int k = 0; k < 6; ++k) {
                float4 v = sv[k];
                a0 = fmaf(v.x, w1[k].x, a0);
                a1 = fmaf(v.y, w1[k].y, a1);
                a2 = fmaf(v.z, w1[k].z, a2);
                a3 = fmaf(v.w, w1[k].w, a3);
            }
            g1part[h1h * 128 + g1] = (a0 + a1) + (a2 + a3);
        } else if (t >= 320 && t < 384) {
            if (step > 0) {
                const int j = t - 320;
                const float ig = g2part[j]       + g2part[256 + j];
                const float gg = g2part[128 + j] + g2part[384 + j];
                const float og = g2part[192 + j] + g2part[448 + j];
                const float cn = sigmoidf_(ig) * tanhf_(gg);
                s12[32 + j] = sigmoidf_(og) * tanhf_(cn);
            }
        } else if (t < 256 + FF) {
            const int f = t - 256;
            sx1[nb][f] = xreg;  // x[step+1]
            const int tn = (step + 2 < TT) ? (step + 2) : (TT - 1);
            xreg = x[(size_t)tn * BB * FF + row * FF + f];
        }
        __syncthreads();

        // ===== P2: h1/c1 update (threads 0..31) =====
        if (t < 32) {
            const float ig = g1part[t]      + g1part[128 + t];
            const float fg = g1part[32 + t] + g1part[160 + t];
            const float gg = g1part[64 + t] + g1part[192 + t];
            const float og = g1part[96 + t] + g1part[224 + t];
            const float cn = sigmoidf_(fg) * c1r + sigmoidf_(ig) * tanhf_(gg);
            c1r = cn;
            const float h = sigmoidf_(og) * tanhf_(cn);
            s12[t] = h;               // for P3 this step
            sx1[nb][16 + t] = h;      // for P1 next step
        }
        __syncthreads();

        // ===== P3: layer-2 half-dots (all 512 threads) =====
        {
            const float4* sv = (const float4*)s12 + h2h * 12;
            float a0 = b2r, a1 = 0.f, a2 = 0.f, a3 = 0.f;
            #pragma unroll
            for (int k = 0; k < 12; ++k) {
                float4 v = sv[k];
                a0 = fmaf(v.x, w2[k].x, a0);
                a1 = fmaf(v.y, w2[k].y, a1);
                a2 = fmaf(v.z, w2[k].z, a2);
                a3 = fmaf(v.w, w2[k].w, a3);
            }
            g2part[h2h * 256 + g2] = (a0 + a1) + (a2 + a3);
        }
        __syncthreads();
    }

    // ---- final h2 update (step TT-1) ----
    if (t < 64) {
        const float ig = g2part[t]       + g2part[256 + t];
        const float gg = g2part[128 + t] + g2part[384 + t];
        const float og = g2part[192 + t] + g2part[448 + t];
        const float cn = sigmoidf_(ig) * tanhf_(gg);
        s12[32 + t] = sigmoidf_(og) * tanhf_(cn);
    }
    __syncthreads();

    // ---- MLP head ----
    if (t < 8) {
        float a = bfc1[t];
        #pragma unroll
        for (int k = 0; k < H2; ++k)
            a = fmaf(fmaxf(s12[32 + k], 0.0f), Wfc1[t * H2 + k], a);
        mlp1[t] = fmaxf(a, 0.0f);
    }
    __syncthreads();
    if (t < 8) {
        float a = bfc2[t];
        #pragma unroll
        for (int k = 0; k < 8; ++k) a = fmaf(mlp1[k], Wfc2[t * 8 + k], a);
        mlp2[t] = fmaxf(a, 0.0f);
    }
    __syncthreads();
    if (t == 0) {
        float a = bfc[0];
        #pragma unroll
        for (int k = 0; k < 8; ++k) a = fmaf(mlp2[k], Wfc[k], a);
        out[row] = a;
    }
}

extern "C" void kernel_launch(void* const* d_in, const int* in_sizes, int n_in,
                              void* d_out, int out_size, void* d_ws, size_t ws_size,
                              hipStream_t stream) {
    const float* x    = (const float*)d_in[0];
    const float* Wih1 = (const float*)d_in[1];
    const float* Whh1 = (const float*)d_in[2];
    const float* bih1 = (const float*)d_in[3];
    const float* bhh1 = (const float*)d_in[4];
    const float* Wih2 = (const float*)d_in[5];
    const float* Whh2 = (const float*)d_in[6];
    const float* bih2 = (const float*)d_in[7];
    const float* bhh2 = (const float*)d_in[8];
    const float* Wfc1 = (const float*)d_in[9];
    const float* bfc1 = (const float*)d_in[10];
    const float* Wfc2 = (const float*)d_in[11];
    const float* bfc2 = (const float*)d_in[12];
    const float* Wfc  = (const float*)d_in[13];
    const float* bfc  = (const float*)d_in[14];
    float* out = (float*)d_out;

    lstm3_kernel<<<dim3(BB), dim3(512), 0, stream>>>(
        x, Wih1, Whh1, bih1, bhh1, Wih2, Whh2, bih2, bhh2,
        Wfc1, bfc1, Wfc2, bfc2, Wfc, bfc, out);
}

// Round 6
// 609.175 us; speedup vs baseline: 1.3877x; 1.1492x over previous
//
#include <hip/hip_runtime.h>
#include <math.h>

#define TT 512
#define BB 512
#define FF 14
#define H1 32
#define H2 64

__device__ __forceinline__ float rcpf_(float x) { return __builtin_amdgcn_rcpf(x); }
__device__ __forceinline__ float sigmoidf_(float x) {
    return rcpf_(1.0f + __expf(-x));
}
__device__ __forceinline__ float tanhf_(float x) {
    float e = __expf(-2.0f * fabsf(x));
    float t = (1.0f - e) * rcpf_(1.0f + e);
    return copysignf(t, x);
}
// Non-rematerializable def: forces the loaded weight to stay live in VGPRs
// across the whole time loop (compiler cannot re-issue the load per step).
__device__ __forceinline__ void pin4(float4& v) {
    asm volatile("" : "+v"(v.x), "+v"(v.y), "+v"(v.z), "+v"(v.w));
}

// NOTE: parameter names must not collide with the .x/.y/.z/.w member tokens.
#define FMA4(vv, ww)                     \
    a0 = fmaf((vv).x, (ww).x, a0);       \
    a1 = fmaf((vv).y, (ww).y, a1);       \
    a2 = fmaf((vv).z, (ww).z, a2);       \
    a3 = fmaf((vv).w, (ww).w, a3);

// One block per batch row, 512 threads (8 waves), 2 blocks/CU (grid-limited:
// 512 blocks / 256 CUs). waves_per_eu(4,4): the grid can only ever reach
// 4 waves/EU, so pin the scheduler's occupancy target there -> 128-VGPR
// budget -> the ~72 weight floats/thread stay register-resident instead of
// being rematerialized from L1/L2 every step (rounds 1-4: VGPR=60..120,
// refetch at the 64 B/cy/CU L1 ceiling).
__global__ __launch_bounds__(512)
__attribute__((amdgpu_waves_per_eu(4, 4)))
void lstm3_kernel(
    const float* __restrict__ x,
    const float* __restrict__ Wih1, const float* __restrict__ Whh1,
    const float* __restrict__ bih1, const float* __restrict__ bhh1,
    const float* __restrict__ Wih2, const float* __restrict__ Whh2,
    const float* __restrict__ bih2, const float* __restrict__ bhh2,
    const float* __restrict__ Wfc1, const float* __restrict__ bfc1,
    const float* __restrict__ Wfc2, const float* __restrict__ bfc2,
    const float* __restrict__ Wfc,  const float* __restrict__ bfc,
    float* __restrict__ out)
{
    const int row = blockIdx.x;
    const int t   = threadIdx.x;

    // s12 = [h1(32) | h2(64)] ; sx1 = [x(14)|pad(2)|h1(32)] double-buffered
    __shared__ __align__(16) float s12[96];
    __shared__ __align__(16) float sx1[2][48];
    __shared__ float g1part[256];   // [half*128 + gate]
    __shared__ float g2part[512];   // [half*256 + gate]
    __shared__ float mlp1[8];
    __shared__ float mlp2[8];

    const int g2  = t & 255;        // layer-2 gate
    const int h2h = t >> 8;         // half of the 96-dot
    const int g1  = t & 127;        // layer-1 gate (t<256)
    const int h1h = (t >> 7) & 1;   // half of the 48-dot

    // ---- layer-2 weights: 12 named float4 (48 floats), register-resident ----
    float4 w2_0, w2_1, w2_2, w2_3, w2_4, w2_5, w2_6, w2_7, w2_8, w2_9, w2_10, w2_11;
    if (h2h == 0) {
        const float4* p = (const float4*)(Wih2 + g2 * H1);
        w2_0 = p[0]; w2_1 = p[1]; w2_2 = p[2]; w2_3 = p[3];
        w2_4 = p[4]; w2_5 = p[5]; w2_6 = p[6]; w2_7 = p[7];
        const float4* q = (const float4*)(Whh2 + g2 * H2);
        w2_8 = q[0]; w2_9 = q[1]; w2_10 = q[2]; w2_11 = q[3];
    } else {
        const float4* q = (const float4*)(Whh2 + g2 * H2);
        w2_0 = q[4];  w2_1 = q[5];  w2_2 = q[6];  w2_3 = q[7];
        w2_4 = q[8];  w2_5 = q[9];  w2_6 = q[10]; w2_7 = q[11];
        w2_8 = q[12]; w2_9 = q[13]; w2_10 = q[14]; w2_11 = q[15];
    }
    pin4(w2_0); pin4(w2_1); pin4(w2_2); pin4(w2_3); pin4(w2_4); pin4(w2_5);
    pin4(w2_6); pin4(w2_7); pin4(w2_8); pin4(w2_9); pin4(w2_10); pin4(w2_11);
    float b2r = (h2h == 0) ? (bih2[g2] + bhh2[g2]) : 0.0f;

    // ---- layer-1 weights: 6 named float4 (24 floats), threads 0..255 ----
    float4 w1_0, w1_1, w1_2, w1_3, w1_4, w1_5;
    float b1r = 0.0f;
    w1_0 = w1_1 = w1_2 = w1_3 = w1_4 = w1_5 = make_float4(0.f, 0.f, 0.f, 0.f);
    if (t < 256) {
        if (h1h == 0) {
            float tmp[16];
            #pragma unroll
            for (int k = 0; k < FF; ++k) tmp[k] = Wih1[g1 * FF + k];
            tmp[14] = 0.0f; tmp[15] = 0.0f;
            w1_0 = make_float4(tmp[0], tmp[1], tmp[2], tmp[3]);
            w1_1 = make_float4(tmp[4], tmp[5], tmp[6], tmp[7]);
            w1_2 = make_float4(tmp[8], tmp[9], tmp[10], tmp[11]);
            w1_3 = make_float4(tmp[12], tmp[13], tmp[14], tmp[15]);
            const float4* q = (const float4*)(Whh1 + g1 * H1);
            w1_4 = q[0];
            w1_5 = q[1];
            b1r = bih1[g1] + bhh1[g1];
        } else {
            const float4* q = (const float4*)(Whh1 + g1 * H1);
            w1_0 = q[2]; w1_1 = q[3]; w1_2 = q[4];
            w1_3 = q[5]; w1_4 = q[6]; w1_5 = q[7];
        }
        pin4(w1_0); pin4(w1_1); pin4(w1_2); pin4(w1_3); pin4(w1_4); pin4(w1_5);
    }

    float c1r  = 0.0f;  // layer-1 cell state, threads 0..31
    float xreg = 0.0f;  // x prefetch, threads 256..269

    if (t < 96) s12[t] = 0.0f;
    if (t < 32) sx1[0][16 + t] = 0.0f;
    if (t >= 256 && t < 256 + FF) {
        const int f = t - 256;
        sx1[0][f] = x[(size_t)0 * BB * FF + row * FF + f];
        xreg      = x[(size_t)1 * BB * FF + row * FF + f];
    }
    if (t == 280) { sx1[0][14] = 0.f; sx1[0][15] = 0.f; sx1[1][14] = 0.f; sx1[1][15] = 0.f; }
    __syncthreads();

    for (int step = 0; step < TT; ++step) {
        const int sb = step & 1;
        const int nb = sb ^ 1;

        // ===== P1 ===== t<256: layer-1 half-dots; [320,384): h2 update of
        // prev step; [256,256+FF): stage x[step+1].
        if (t < 256) {
            const float4* sv = (const float4*)(sx1[sb]) + h1h * 6;
            float a0 = b1r, a1 = 0.f, a2 = 0.f, a3 = 0.f;
            float4 v;
            v = sv[0]; FMA4(v, w1_0);
            v = sv[1]; FMA4(v, w1_1);
            v = sv[2]; FMA4(v, w1_2);
            v = sv[3]; FMA4(v, w1_3);
            v = sv[4]; FMA4(v, w1_4);
            v = sv[5]; FMA4(v, w1_5);
            g1part[h1h * 128 + g1] = (a0 + a1) + (a2 + a3);
        } else if (t >= 320 && t < 384) {
            if (step > 0) {
                const int j = t - 320;
                const float ig = g2part[j]       + g2part[256 + j];
                const float gg = g2part[128 + j] + g2part[384 + j];
                const float og = g2part[192 + j] + g2part[448 + j];
                const float cn = sigmoidf_(ig) * tanhf_(gg);
                s12[32 + j] = sigmoidf_(og) * tanhf_(cn);
            }
        } else if (t < 256 + FF) {
            const int f = t - 256;
            sx1[nb][f] = xreg;  // x[step+1]
            const int tn = (step + 2 < TT) ? (step + 2) : (TT - 1);
            xreg = x[(size_t)tn * BB * FF + row * FF + f];
        }
        __syncthreads();

        // ===== P2: h1/c1 update (threads 0..31) =====
        if (t < 32) {
            const float ig = g1part[t]      + g1part[128 + t];
            const float fg = g1part[32 + t] + g1part[160 + t];
            const float gg = g1part[64 + t] + g1part[192 + t];
            const float og = g1part[96 + t] + g1part[224 + t];
            const float cn = sigmoidf_(fg) * c1r + sigmoidf_(ig) * tanhf_(gg);
            c1r = cn;
            const float h = sigmoidf_(og) * tanhf_(cn);
            s12[t] = h;               // for P3 this step
            sx1[nb][16 + t] = h;      // for P1 next step
        }
        __syncthreads();

        // ===== P3: layer-2 half-dots (all 512 threads) =====
        {
            const float4* sv = (const float4*)s12 + h2h * 12;
            float a0 = b2r, a1 = 0.f, a2 = 0.f, a3 = 0.f;
            float4 v;
            v = sv[0];  FMA4(v, w2_0);
            v = sv[1];  FMA4(v, w2_1);
            v = sv[2];  FMA4(v, w2_2);
            v = sv[3];  FMA4(v, w2_3);
            v = sv[4];  FMA4(v, w2_4);
            v = sv[5];  FMA4(v, w2_5);
            v = sv[6];  FMA4(v, w2_6);
            v = sv[7];  FMA4(v, w2_7);
            v = sv[8];  FMA4(v, w2_8);
            v = sv[9];  FMA4(v, w2_9);
            v = sv[10]; FMA4(v, w2_10);
            v = sv[11]; FMA4(v, w2_11);
            g2part[h2h * 256 + g2] = (a0 + a1) + (a2 + a3);
        }
        __syncthreads();
    }

    // ---- final h2 update (step TT-1) ----
    if (t < 64) {
        const float ig = g2part[t]       + g2part[256 + t];
        const float gg = g2part[128 + t] + g2part[384 + t];
        const float og = g2part[192 + t] + g2part[448 + t];
        const float cn = sigmoidf_(ig) * tanhf_(gg);
        s12[32 + t] = sigmoidf_(og) * tanhf_(cn);
    }
    __syncthreads();

    // ---- MLP head ----
    if (t < 8) {
        float a = bfc1[t];
        #pragma unroll
        for (int k = 0; k < H2; ++k)
            a = fmaf(fmaxf(s12[32 + k], 0.0f), Wfc1[t * H2 + k], a);
        mlp1[t] = fmaxf(a, 0.0f);
    }
    __syncthreads();
    if (t < 8) {
        float a = bfc2[t];
        #pragma unroll
        for (int k = 0; k < 8; ++k) a = fmaf(mlp1[k], Wfc2[t * 8 + k], a);
        mlp2[t] = fmaxf(a, 0.0f);
    }
    __syncthreads();
    if (t == 0) {
        float a = bfc[0];
        #pragma unroll
        for (int k = 0; k < 8; ++k) a = fmaf(mlp2[k], Wfc[k], a);
        out[row] = a;
    }
}

extern "C" void kernel_launch(void* const* d_in, const int* in_sizes, int n_in,
                              void* d_out, int out_size, void* d_ws, size_t ws_size,
                              hipStream_t stream) {
    const float* x    = (const float*)d_in[0];
    const float* Wih1 = (const float*)d_in[1];
    const float* Whh1 = (const float*)d_in[2];
    const float* bih1 = (const float*)d_in[3];
    const float* bhh1 = (const float*)d_in[4];
    const float* Wih2 = (const float*)d_in[5];
    const float* Whh2 = (const float*)d_in[6];
    const float* bih2 = (const float*)d_in[7];
    const float* bhh2 = (const float*)d_in[8];
    const float* Wfc1 = (const float*)d_in[9];
    const float* bfc1 = (const float*)d_in[10];
    const float* Wfc2 = (const float*)d_in[11];
    const float* bfc2 = (const float*)d_in[12];
    const float* Wfc  = (const float*)d_in[13];
    const float* bfc  = (const float*)d_in[14];
    float* out = (float*)d_out;

    lstm3_kernel<<<dim3(BB), dim3(512), 0, stream>>>(
        x, Wih1, Whh1, bih1, bhh1, Wih2, Whh2, bih2, bhh2,
        Wfc1, bfc1, Wfc2, bfc2, Wfc, bfc, out);
}